// Round 2
// baseline (1314.653 us; speedup 1.0000x reference)
//
#include <hip/hip_runtime.h>

#define TSTEPS 2048
#define BCOLS  8192
#define TBSZ   (TSTEPS * BCOLS)
#define CHUNKS 32
#define CLEN   64          // TSTEPS / CHUNKS
#define NGRP   128         // BCOLS / 64 column groups (one wave each)
#define PBLK   32          // producer blocks: 32 x 256thr = 128 waves = 128 groups
#define NCONS  512         // consumer blocks; each handles 2 chunks (c, c+16)
#define RING   32          // producer prefetch ring depth

// One SEIR step. Shared by all kernels so rounding is identical everywhere.
__device__ __forceinline__ void seir_step(float x, float wb, float wg, float wsg,
                                          float invN,
                                          float& S, float& E, float& I, float& R)
{
    const float s2e = x * wb * I * S * invN;
    const float e2i = x * wsg * E;
    const float i2r = x * wg * I;
    S = S - s2e;
    E = E + s2e - e2i;
    I = I + e2i - i2r;
    R = R + i2r;
}

// ---------------------------------------------------------------------------
// Replay one chunk from a known start state, streaming all outputs.
// Identical to the 378us-verified pass2 inner loop.
// ---------------------------------------------------------------------------
template <int NS>
__device__ __forceinline__ void run_chunk(const float* __restrict__ xp,
                                          float* __restrict__ pS,
                                          float* __restrict__ pE,
                                          float* __restrict__ pI,
                                          float* __restrict__ pR,
                                          float wb, float wg, float wsg, float invN,
                                          float S, float E, float I, float R)
{
    float xbuf[8];
#pragma unroll
    for (int k = 0; k < 8; ++k)
        xbuf[k] = xp[(size_t)k * BCOLS];
#pragma unroll
    for (int t = 0; t < NS; ++t) {
        const float x = xbuf[t & 7];
        if (t + 8 < NS)
            xbuf[t & 7] = xp[(size_t)(t + 8) * BCOLS];
        seir_step(x, wb, wg, wsg, invN, S, E, I, R);
        __builtin_nontemporal_store(S, pS + (size_t)t * BCOLS);
        __builtin_nontemporal_store(E, pE + (size_t)t * BCOLS);
        __builtin_nontemporal_store(I, pI + (size_t)t * BCOLS);
        __builtin_nontemporal_store(R, pR + (size_t)t * BCOLS);
    }
}

// ---------------------------------------------------------------------------
// Consumer side: process one 64-row chunk for this thread's column b.
// Chunk 0 starts from the initial state; chunk c>=1 acquire-polls the
// producer's flag for this 64-col group. On timeout (pathological
// scheduling only) it recomputes the start state itself from t=0 — slow
// but bit-identical, so the kernel can NEVER hang or go wrong.
// ---------------------------------------------------------------------------
__device__ __forceinline__ void consume_chunk(
    int c, int b, int g,
    const float* __restrict__ X,
    const float* __restrict__ S0, const float* __restrict__ I0,
    const float* __restrict__ R0,
    const float* __restrict__ wsp, const unsigned* __restrict__ flags,
    float* __restrict__ out,
    float wb, float wg, float wsg, float invN)
{
    float* oS = out + b;
    float* oE = out + (size_t)TBSZ + b;
    float* oI = out + (size_t)2 * TBSZ + b;
    float* oR = out + (size_t)3 * TBSZ + b;

    if (c == 0) {
        float S = S0[b];
        float E = 0.0f;
        float I = I0[b];
        float R = R0[b];
        __builtin_nontemporal_store(S, oS);
        __builtin_nontemporal_store(0.0f, oE);
        __builtin_nontemporal_store(I, oI);
        __builtin_nontemporal_store(R, oR);
        run_chunk<63>(X + b,
                      oS + BCOLS, oE + BCOLS, oI + BCOLS, oR + BCOLS,
                      wb, wg, wsg, invN, S, E, I, R);
        return;
    }

    const unsigned* fp = &flags[(c - 1) * NGRP + g];
    unsigned f;
    int spins = 0;
    while ((f = __hip_atomic_load(fp, __ATOMIC_ACQUIRE,
                                  __HIP_MEMORY_SCOPE_AGENT)) == 0u) {
        __builtin_amdgcn_s_sleep(8);
        if (++spins > (1 << 20)) break;     // ~0.2 s cap, then self-compute
    }

    float S, E, I, R;
    if (f != 0u) {
        const float* wp = wsp + (size_t)(c - 1) * 4 * BCOLS + b;
        S = wp[0];
        E = wp[(size_t)BCOLS];
        I = wp[(size_t)2 * BCOLS];
        R = wp[(size_t)3 * BCOLS];
    } else {
        // correctness safety net: serial replay from the initial state
        S = S0[b];
        E = 0.0f;
        I = I0[b];
        R = R0[b];
        const float* xq = X + b;
        const int nst = 64 * c - 1;          // consume rows 0 .. 64c-2
#pragma unroll 4
        for (int t = 0; t < nst; ++t)
            seir_step(xq[(size_t)t * BCOLS], wb, wg, wsg, invN, S, E, I, R);
    }

    const size_t t0 = (size_t)c * CLEN - 1;  // first X row consumed
    const size_t r0 = (size_t)c * CLEN;      // first output row written
    run_chunk<64>(X + t0 * BCOLS + b,
                  oS + r0 * BCOLS, oE + r0 * BCOLS,
                  oI + r0 * BCOLS, oR + r0 * BCOLS,
                  wb, wg, wsg, invN, S, E, I, R);
}

// ---------------------------------------------------------------------------
// Fused producer/consumer kernel.
//   blocks [0, PBLK)        : producers. Each wave owns 64 columns, runs the
//                             serial sweep t = 0..1982, publishing the 31
//                             chunk-boundary states with agent-release flags.
//   blocks [PBLK, PBLK+512) : consumers. Block -> 256-col group G; handles
//                             chunks c and c+16 in order.
// Residency: 544 blocks, 0 LDS, __launch_bounds__(256,4) caps VGPR at 128
// (producer needs ~60) -> >=4 blocks/CU -> capacity 1024 >= 544: all blocks
// co-resident with 2x slack. Even if that fails, the consumer timeout
// fallback guarantees termination + correctness.
// ---------------------------------------------------------------------------
__global__ __launch_bounds__(256, 4)
void seir_fused(const float* __restrict__ X,
                const float* __restrict__ w_beta,
                const float* __restrict__ w_gamma,
                const float* __restrict__ w_sigma,
                const float* __restrict__ S0,
                const float* __restrict__ I0,
                const float* __restrict__ R0,
                const float* __restrict__ Nv,
                float* __restrict__ wsp,
                unsigned* __restrict__ flags,
                float* __restrict__ out)
{
    const int wave = threadIdx.x >> 6;
    const int lane = threadIdx.x & 63;

    if (blockIdx.x < PBLK) {
        // ------------------------------ producer ------------------------------
        const int g = blockIdx.x * 4 + wave;   // 64-col group 0..127
        const int b = g * 64 + lane;

        __builtin_amdgcn_s_setprio(1);         // serial chain wins issue arbitration

        const float wb  = w_beta[b];
        const float wg  = w_gamma[b];
        const float wsg = w_sigma[b];
        const float invN = 1.0f / Nv[b];
        float S = S0[b];
        float E = 0.0f;
        float I = I0[b];
        float R = R0[b];

        const float* xp = X + b;
        float ring[RING];
#pragma unroll
        for (int k = 0; k < RING; ++k)
            ring[k] = xp[(size_t)k * BCOLS];
        xp += (size_t)RING * BCOLS;

        // 61 blocks of 32 steps: consumes rows t = 32j + k, t = 0..1951.
        // Boundary after consuming row t ≡ 62 (mod 64)  <=>  k==30 && (j odd);
        // idx = (j-1)/2 = 0..29.
        for (int j = 0; j < 61; ++j) {
#pragma unroll
            for (int k = 0; k < RING; ++k) {
                const float x = ring[k];
                ring[k] = xp[(size_t)k * BCOLS];   // prefetch row 32*(j+1)+k (<=1983)
                seir_step(x, wb, wg, wsg, invN, S, E, I, R);
                if (k == 30 && (j & 1)) {
                    const int idx = (j - 1) >> 1;
                    float* wp = wsp + (size_t)idx * 4 * BCOLS + b;
                    wp[0]                 = S;
                    wp[(size_t)BCOLS]     = E;
                    wp[(size_t)2 * BCOLS] = I;
                    wp[(size_t)3 * BCOLS] = R;
                    if (lane == 0)
                        __hip_atomic_store(&flags[idx * NGRP + g], 1u,
                                           __ATOMIC_RELEASE,
                                           __HIP_MEMORY_SCOPE_AGENT);
                }
            }
            xp += (size_t)RING * BCOLS;
        }
        // drain: rows 1952..1982 from ring[0..30]; last step is boundary idx 30
#pragma unroll
        for (int k = 0; k < 31; ++k)
            seir_step(ring[k], wb, wg, wsg, invN, S, E, I, R);
        {
            float* wp = wsp + (size_t)30 * 4 * BCOLS + b;
            wp[0]                 = S;
            wp[(size_t)BCOLS]     = E;
            wp[(size_t)2 * BCOLS] = I;
            wp[(size_t)3 * BCOLS] = R;
            if (lane == 0)
                __hip_atomic_store(&flags[30 * NGRP + g], 1u,
                                   __ATOMIC_RELEASE, __HIP_MEMORY_SCOPE_AGENT);
        }
    } else {
        // ------------------------------ consumer ------------------------------
        const int idx = (int)blockIdx.x - PBLK;       // 0..511
        const int G   = idx & 31;                     // 256-col group
        const int cp  = idx >> 5;                     // 0..15
        const int g   = G * 4 + wave;                 // 64-col group 0..127
        const int b   = g * 64 + lane;

        const float wb  = w_beta[b];
        const float wg  = w_gamma[b];
        const float wsg = w_sigma[b];
        const float invN = 1.0f / Nv[b];

        consume_chunk(cp, b, g, X, S0, I0, R0, wsp, flags, out,
                      wb, wg, wsg, invN);
        consume_chunk(cp + 16, b, g, X, S0, I0, R0, wsp, flags, out,
                      wb, wg, wsg, invN);
    }
}

// ---------------------------------------------------------------------------
// Fallback: single-kernel version (used only if ws_size is too small).
// ---------------------------------------------------------------------------
__global__ __launch_bounds__(64)
void seir_mono(const float* __restrict__ X,
               const float* __restrict__ w_beta,
               const float* __restrict__ w_gamma,
               const float* __restrict__ w_sigma,
               const float* __restrict__ S0,
               const float* __restrict__ I0,
               const float* __restrict__ R0,
               const float* __restrict__ Nv,
               float* __restrict__ out)
{
    const int b = blockIdx.x * 64 + threadIdx.x;
    const float wb  = w_beta[b];
    const float wg  = w_gamma[b];
    const float wsg = w_sigma[b];
    float S = S0[b];
    float E = 0.0f;
    float I = I0[b];
    float R = R0[b];
    const float invN = 1.0f / Nv[b];

    float* oS = out + b;
    float* oE = out + (size_t)TBSZ + b;
    float* oI = out + (size_t)2 * TBSZ + b;
    float* oR = out + (size_t)3 * TBSZ + b;

    __builtin_nontemporal_store(S, oS);
    __builtin_nontemporal_store(0.0f, oE);
    __builtin_nontemporal_store(I, oI);
    __builtin_nontemporal_store(R, oR);

    const float* xp = X + b;
    float xc[8];
#pragma unroll
    for (int k = 0; k < 8; ++k)
        xc[k] = __builtin_nontemporal_load(xp + (size_t)k * BCOLS);
    xp += (size_t)8 * BCOLS;

    for (int i = 0; i < 255; ++i) {
        float xn[8];
#pragma unroll
        for (int k = 0; k < 8; ++k)
            xn[k] = __builtin_nontemporal_load(xp + (size_t)k * BCOLS);
        xp += (size_t)8 * BCOLS;

        float* pS = oS + (size_t)(8 * i + 1) * BCOLS;
        float* pE = oE + (size_t)(8 * i + 1) * BCOLS;
        float* pI = oI + (size_t)(8 * i + 1) * BCOLS;
        float* pR = oR + (size_t)(8 * i + 1) * BCOLS;

#pragma unroll
        for (int k = 0; k < 8; ++k) {
            seir_step(xc[k], wb, wg, wsg, invN, S, E, I, R);
            __builtin_nontemporal_store(S, pS + (size_t)k * BCOLS);
            __builtin_nontemporal_store(E, pE + (size_t)k * BCOLS);
            __builtin_nontemporal_store(I, pI + (size_t)k * BCOLS);
            __builtin_nontemporal_store(R, pR + (size_t)k * BCOLS);
        }
#pragma unroll
        for (int k = 0; k < 8; ++k) xc[k] = xn[k];
    }
    {
        float* pS = oS + (size_t)2041 * BCOLS;
        float* pE = oE + (size_t)2041 * BCOLS;
        float* pI = oI + (size_t)2041 * BCOLS;
        float* pR = oR + (size_t)2041 * BCOLS;
#pragma unroll
        for (int k = 0; k < 7; ++k) {
            seir_step(xc[k], wb, wg, wsg, invN, S, E, I, R);
            __builtin_nontemporal_store(S, pS + (size_t)k * BCOLS);
            __builtin_nontemporal_store(E, pE + (size_t)k * BCOLS);
            __builtin_nontemporal_store(I, pI + (size_t)k * BCOLS);
            __builtin_nontemporal_store(R, pR + (size_t)k * BCOLS);
        }
    }
}

extern "C" void kernel_launch(void* const* d_in, const int* in_sizes, int n_in,
                              void* d_out, int out_size, void* d_ws, size_t ws_size,
                              hipStream_t stream)
{
    (void)in_sizes; (void)n_in; (void)out_size;

    const float* X      = (const float*)d_in[0];
    const float* w_beta = (const float*)d_in[1];
    const float* w_gamma= (const float*)d_in[2];
    const float* w_sigma= (const float*)d_in[3];
    const float* S0     = (const float*)d_in[4];
    const float* I0     = (const float*)d_in[5];
    const float* R0     = (const float*)d_in[6];
    const float* Nv     = (const float*)d_in[7];
    float* out          = (float*)d_out;

    const size_t state_bytes = (size_t)(CHUNKS - 1) * 4 * BCOLS * sizeof(float); // ~3.9 MB
    const size_t flag_bytes  = (size_t)(CHUNKS - 1) * NGRP * sizeof(unsigned);   // ~15.9 KB
    if (ws_size < state_bytes + flag_bytes) {
        seir_mono<<<dim3(BCOLS / 64), dim3(64), 0, stream>>>(
            X, w_beta, w_gamma, w_sigma, S0, I0, R0, Nv, out);
        return;
    }

    float* wsp      = (float*)d_ws;
    unsigned* flags = (unsigned*)((char*)d_ws + state_bytes);

    // Flags live in poisoned workspace: zero them every launch (graph-legal).
    hipMemsetAsync(flags, 0, flag_bytes, stream);

    seir_fused<<<dim3(PBLK + NCONS), dim3(256), 0, stream>>>(
        X, w_beta, w_gamma, w_sigma, S0, I0, R0, Nv, wsp, flags, out);
}